// Round 3
// baseline (9603.687 us; speedup 1.0000x reference)
//
#include <hip/hip_runtime.h>

// RNN: B=64, T=512, I=1024, H=1024, fp32.
// Phase 1: xproj = x @ Wx + bx + bh  -> d_out
// Phase 2: persistent scan; 256 blocks (512 thr) = 8 batch-groups x 32 col-groups.
//   - Wh slice in registers: 16 float4/thread (64 VGPR) for all 512 steps
//   - h exchange: TAGGED 8B slots {step, h} via relaxed agent-scope atomics.
//     No fences, no flags, no leader, no producer-side waits. Consumers
//     retry-load until tag >= t. Double buffer => slot for step t can only be
//     overwritten (by t+2) after every block consumed step t. Tags cleared by
//     1MiB memset each launch (graph-replay safe).

#define Bdim 64
#define Tdim 512
#define Idim 1024
#define Hdim 1024
#define Mdim (Bdim * Tdim)  // 32768

__device__ __forceinline__ float tanh_fast(float x) {
  float e = __expf(2.0f * x);
  return 1.0f - 2.0f / (e + 1.0f);
}

// ---------------- Phase 1: xproj GEMM (fp32 SIMT, 128x128 tile, 8x8/thread) --
#define BM 128
#define BN 128
#define BK 16

__global__ __launch_bounds__(256) void xproj_gemm(
    const float* __restrict__ A,   // x  [M=32768][K=1024]
    const float* __restrict__ W,   // Wx [K=1024][N=1024]
    const float* __restrict__ bx,  // [N]
    const float* __restrict__ bh,  // [N]
    float* __restrict__ C) {       // [M][N]
  __shared__ float As[BK][BM];
  __shared__ float Bs[BK][BN];
  const int tid = threadIdx.x;
  const int m0 = blockIdx.y * BM;
  const int n0 = blockIdx.x * BN;
  const int ty = tid >> 4;
  const int tx = tid & 15;
  const int ar = tid & 127;
  const int ah = tid >> 7;
  const int bk = tid >> 4;
  const int bs = tid & 15;

  float acc[8][8];
#pragma unroll
  for (int i = 0; i < 8; ++i)
#pragma unroll
    for (int j = 0; j < 8; ++j) acc[i][j] = 0.f;

  for (int k0 = 0; k0 < Idim; k0 += BK) {
    float4 a0 = *(const float4*)&A[(size_t)(m0 + ar) * Idim + k0 + ah * 8];
    float4 a1 = *(const float4*)&A[(size_t)(m0 + ar) * Idim + k0 + ah * 8 + 4];
    float4 b0 = *(const float4*)&W[(size_t)(k0 + bk) * Hdim + n0 + bs * 8];
    float4 b1 = *(const float4*)&W[(size_t)(k0 + bk) * Hdim + n0 + bs * 8 + 4];
    __syncthreads();
    As[ah * 8 + 0][ar] = a0.x; As[ah * 8 + 1][ar] = a0.y;
    As[ah * 8 + 2][ar] = a0.z; As[ah * 8 + 3][ar] = a0.w;
    As[ah * 8 + 4][ar] = a1.x; As[ah * 8 + 5][ar] = a1.y;
    As[ah * 8 + 6][ar] = a1.z; As[ah * 8 + 7][ar] = a1.w;
    *(float4*)&Bs[bk][bs * 8] = b0;
    *(float4*)&Bs[bk][bs * 8 + 4] = b1;
    __syncthreads();
#pragma unroll
    for (int kk = 0; kk < BK; ++kk) {
      float4 x0 = *(const float4*)&As[kk][ty * 8];
      float4 x1 = *(const float4*)&As[kk][ty * 8 + 4];
      float4 y0 = *(const float4*)&Bs[kk][tx * 8];
      float4 y1 = *(const float4*)&Bs[kk][tx * 8 + 4];
      float av[8] = {x0.x, x0.y, x0.z, x0.w, x1.x, x1.y, x1.z, x1.w};
      float bv[8] = {y0.x, y0.y, y0.z, y0.w, y1.x, y1.y, y1.z, y1.w};
#pragma unroll
      for (int i = 0; i < 8; ++i)
#pragma unroll
        for (int j = 0; j < 8; ++j)
          acc[i][j] = fmaf(av[i], bv[j], acc[i][j]);
    }
  }
  float bias[8];
#pragma unroll
  for (int j = 0; j < 8; ++j) bias[j] = bx[n0 + tx * 8 + j] + bh[n0 + tx * 8 + j];
#pragma unroll
  for (int i = 0; i < 8; ++i) {
    float4 o0, o1;
    o0.x = acc[i][0] + bias[0]; o0.y = acc[i][1] + bias[1];
    o0.z = acc[i][2] + bias[2]; o0.w = acc[i][3] + bias[3];
    o1.x = acc[i][4] + bias[4]; o1.y = acc[i][5] + bias[5];
    o1.z = acc[i][6] + bias[6]; o1.w = acc[i][7] + bias[7];
    size_t off = (size_t)(m0 + ty * 8 + i) * Hdim + n0 + tx * 8;
    *(float4*)&C[off] = o0;
    *(float4*)&C[off + 4] = o1;
  }
}

// ---------------- Phase 2: persistent recurrent scan ------------------------
// 512 threads = 8 waves. wave w, lane l: kgrp=l/8, cq=l%8.
// Thread holds Wh[w*128+kgrp*16 .. +16)[cbase+cq*4 .. +4) : 16 float4 = 64 VGPR.
__global__ __launch_bounds__(512, 2) void rnn_scan(
    const float* __restrict__ Wh,        // [H][H]
    float* __restrict__ out,             // [B][T][H]: xproj in, h out
    float* __restrict__ hlast,           // [B][H]
    unsigned long long* hbuf) {          // ws: [2][64][1024] tagged {step,h}
  const int bid = blockIdx.x;
  const int bg = bid & 7;          // batch group (8 batches)
  const int cg = bid >> 3;         // col group (32 cols)
  const int tid = threadIdx.x;
  const int w = tid >> 6;          // wave 0..7
  const int l = tid & 63;
  const int kgrp = l >> 3;
  const int cq = l & 7;
  const int kbase = w * 128 + kgrp * 16;
  const int cbase = cg * 32;
  const int c4 = cq * 4;
  const int batch0 = bg * 8;

  __shared__ float h_lds[8192] __attribute__((aligned(16)));   // 32 KB
  __shared__ float part[8][8][32] __attribute__((aligned(16))); // 8 KB

  // Persistent Wh slice (16 float4 per thread)
  float4 wh4[16];
#pragma unroll
  for (int i = 0; i < 16; ++i)
    wh4[i] = *(const float4*)&Wh[(size_t)(kbase + i) * Hdim + cbase + c4];

  const bool fin = tid < 256;       // finisher: owns one (batch,col) output
  const int fb = (tid >> 5) & 7;
  const int fc = tid & 31;
  const size_t orow = (size_t)(batch0 + fb) * ((size_t)Tdim * Hdim) + cbase + fc;
  const size_t hrow = (size_t)(batch0 + fb) * Hdim + cbase + fc;

  float xp = fin ? out[orow] : 0.f;  // xproj for t=0

  for (int t = 0; t < Tdim; ++t) {
    float sum = 0.f;
    if (t > 0) {
      // ---- stage tagged h (tag >= t means fresh) ----
      const unsigned long long* src = hbuf + (size_t)(t & 1) * 65536 +
                                      (size_t)batch0 * 1024 + (size_t)tid * 16;
      unsigned long long v[16];
      const unsigned int tgt = (unsigned int)t;
      for (;;) {
        bool ok = true;
#pragma unroll
        for (int i = 0; i < 16; ++i)
          v[i] = __hip_atomic_load(&src[i], __ATOMIC_RELAXED,
                                   __HIP_MEMORY_SCOPE_AGENT);
#pragma unroll
        for (int i = 0; i < 16; ++i)
          ok &= ((unsigned int)(v[i] >> 32) >= tgt);
        if (ok) break;
        __builtin_amdgcn_s_sleep(1);
      }
      const int L0 = tid * 16;
#pragma unroll
      for (int g = 0; g < 4; ++g) {
        int L = L0 + g * 4;
        int sw = L ^ (((L >> 5) & 7) << 2);
        float4 f;
        f.x = __uint_as_float((unsigned int)v[g * 4 + 0]);
        f.y = __uint_as_float((unsigned int)v[g * 4 + 1]);
        f.z = __uint_as_float((unsigned int)v[g * 4 + 2]);
        f.w = __uint_as_float((unsigned int)v[g * 4 + 3]);
        *(float4*)&h_lds[sw] = f;
      }
      __syncthreads();
      // ---- compute: 8 batches x 4 cols x 16 k per thread ----
#pragma unroll
      for (int b = 0; b < 8; ++b) {
        float p0 = 0.f, p1 = 0.f, p2 = 0.f, p3 = 0.f;
        const int Lb = b * 1024 + kbase;
#pragma unroll
        for (int q = 0; q < 4; ++q) {
          int L = Lb + q * 4;
          int sw = L ^ (((L >> 5) & 7) << 2);
          float4 hv = *(const float4*)&h_lds[sw];
          float4 wa = wh4[4 * q + 0], wb = wh4[4 * q + 1];
          float4 wc = wh4[4 * q + 2], wd = wh4[4 * q + 3];
          p0 = fmaf(hv.x, wa.x, p0); p0 = fmaf(hv.y, wb.x, p0);
          p0 = fmaf(hv.z, wc.x, p0); p0 = fmaf(hv.w, wd.x, p0);
          p1 = fmaf(hv.x, wa.y, p1); p1 = fmaf(hv.y, wb.y, p1);
          p1 = fmaf(hv.z, wc.y, p1); p1 = fmaf(hv.w, wd.y, p1);
          p2 = fmaf(hv.x, wa.z, p2); p2 = fmaf(hv.y, wb.z, p2);
          p2 = fmaf(hv.z, wc.z, p2); p2 = fmaf(hv.w, wd.z, p2);
          p3 = fmaf(hv.x, wa.w, p3); p3 = fmaf(hv.y, wb.w, p3);
          p3 = fmaf(hv.z, wc.w, p3); p3 = fmaf(hv.w, wd.w, p3);
        }
        // butterfly over kgrp (lane bits 3..5)
        p0 += __shfl_xor(p0, 8);  p0 += __shfl_xor(p0, 16); p0 += __shfl_xor(p0, 32);
        p1 += __shfl_xor(p1, 8);  p1 += __shfl_xor(p1, 16); p1 += __shfl_xor(p1, 32);
        p2 += __shfl_xor(p2, 8);  p2 += __shfl_xor(p2, 16); p2 += __shfl_xor(p2, 32);
        p3 += __shfl_xor(p3, 8);  p3 += __shfl_xor(p3, 16); p3 += __shfl_xor(p3, 32);
        if (kgrp == b)
          *(float4*)&part[w][b][c4] = make_float4(p0, p1, p2, p3);
      }
      __syncthreads();
      if (fin) {
        sum = part[0][fb][fc] + part[1][fb][fc] + part[2][fb][fc] +
              part[3][fb][fc] + part[4][fb][fc] + part[5][fb][fc] +
              part[6][fb][fc] + part[7][fb][fc];
      }
    }
    if (fin) {
      float h = tanh_fast(xp + sum);
      if (t < Tdim - 1) {
        // publish FIRST (critical path), then the HBM output store
        unsigned long long pv =
            ((unsigned long long)(unsigned int)(t + 1) << 32) |
            (unsigned long long)__float_as_uint(h);
        __hip_atomic_store(&hbuf[(size_t)((t + 1) & 1) * 65536 + hrow], pv,
                           __ATOMIC_RELAXED, __HIP_MEMORY_SCOPE_AGENT);
        __builtin_nontemporal_store(h, &out[orow + (size_t)t * Hdim]);
        xp = __builtin_nontemporal_load(&out[orow + (size_t)(t + 1) * Hdim]);
      } else {
        __builtin_nontemporal_store(h, &out[orow + (size_t)t * Hdim]);
        hlast[hrow] = h;
      }
    }
  }
}

extern "C" void kernel_launch(void* const* d_in, const int* in_sizes, int n_in,
                              void* d_out, int out_size, void* d_ws,
                              size_t ws_size, hipStream_t stream) {
  const float* x  = (const float*)d_in[0];
  const float* Wx = (const float*)d_in[1];
  const float* bx = (const float*)d_in[2];
  const float* Wh = (const float*)d_in[3];
  const float* bh = (const float*)d_in[4];
  float* out = (float*)d_out;
  float* hlast = out + (size_t)Bdim * Tdim * Hdim;
  unsigned long long* hbuf = (unsigned long long*)d_ws;

  // clear tags each launch (ws is NOT re-poisoned between graph replays)
  hipMemsetAsync(d_ws, 0, 2ull * 65536ull * 8ull, stream);

  dim3 g1(Hdim / BN, Mdim / BM);  // (8, 256)
  xproj_gemm<<<g1, dim3(256), 0, stream>>>(x, Wx, bx, bh, out);
  rnn_scan<<<dim3(256), dim3(512), 0, stream>>>(Wh, out, hlast, hbuf);
}

// Round 4
// 5285.953 us; speedup vs baseline: 1.8168x; 1.8168x over previous
//
#include <hip/hip_runtime.h>

// RNN: B=64, T=512, I=1024, H=1024, fp32.
// Phase 1: xproj = x @ Wx + bx + bh  -> d_out
// Phase 2: persistent scan; 256 blocks (512 thr) = 8 batch-groups x 32 col-groups.
//   - Wh slice in registers: 16 float4/thread, PINNED via empty asm so the
//     compiler cannot sink the loads into the t-loop (round-3 bug: VGPR=76
//     proved Wh was re-fetched from cache every step).
//   - h exchange: fp32 agent-scope relaxed atomic stores (write-through to the
//     coherence point, no fences); per-block flag after the __syncthreads
//     vmcnt-drain; wave 0 polls the cluster's 32 flags (one 128B line).

#define Bdim 64
#define Tdim 512
#define Idim 1024
#define Hdim 1024
#define Mdim (Bdim * Tdim)  // 32768

__device__ __forceinline__ float tanh_fast(float x) {
  float e = __expf(2.0f * x);
  return 1.0f - 2.0f / (e + 1.0f);
}

// ---------------- Phase 1: xproj GEMM (fp32 SIMT, 128x128 tile, 8x8/thread) --
#define BM 128
#define BN 128
#define BK 16

__global__ __launch_bounds__(256) void xproj_gemm(
    const float* __restrict__ A,   // x  [M=32768][K=1024]
    const float* __restrict__ W,   // Wx [K=1024][N=1024]
    const float* __restrict__ bx,  // [N]
    const float* __restrict__ bh,  // [N]
    float* __restrict__ C) {       // [M][N]
  __shared__ float As[BK][BM];
  __shared__ float Bs[BK][BN];
  const int tid = threadIdx.x;
  const int m0 = blockIdx.y * BM;
  const int n0 = blockIdx.x * BN;
  const int ty = tid >> 4;
  const int tx = tid & 15;
  const int ar = tid & 127;
  const int ah = tid >> 7;
  const int bk = tid >> 4;
  const int bs = tid & 15;

  float acc[8][8];
#pragma unroll
  for (int i = 0; i < 8; ++i)
#pragma unroll
    for (int j = 0; j < 8; ++j) acc[i][j] = 0.f;

  for (int k0 = 0; k0 < Idim; k0 += BK) {
    float4 a0 = *(const float4*)&A[(size_t)(m0 + ar) * Idim + k0 + ah * 8];
    float4 a1 = *(const float4*)&A[(size_t)(m0 + ar) * Idim + k0 + ah * 8 + 4];
    float4 b0 = *(const float4*)&W[(size_t)(k0 + bk) * Hdim + n0 + bs * 8];
    float4 b1 = *(const float4*)&W[(size_t)(k0 + bk) * Hdim + n0 + bs * 8 + 4];
    __syncthreads();
    As[ah * 8 + 0][ar] = a0.x; As[ah * 8 + 1][ar] = a0.y;
    As[ah * 8 + 2][ar] = a0.z; As[ah * 8 + 3][ar] = a0.w;
    As[ah * 8 + 4][ar] = a1.x; As[ah * 8 + 5][ar] = a1.y;
    As[ah * 8 + 6][ar] = a1.z; As[ah * 8 + 7][ar] = a1.w;
    *(float4*)&Bs[bk][bs * 8] = b0;
    *(float4*)&Bs[bk][bs * 8 + 4] = b1;
    __syncthreads();
#pragma unroll
    for (int kk = 0; kk < BK; ++kk) {
      float4 x0 = *(const float4*)&As[kk][ty * 8];
      float4 x1 = *(const float4*)&As[kk][ty * 8 + 4];
      float4 y0 = *(const float4*)&Bs[kk][tx * 8];
      float4 y1 = *(const float4*)&Bs[kk][tx * 8 + 4];
      float av[8] = {x0.x, x0.y, x0.z, x0.w, x1.x, x1.y, x1.z, x1.w};
      float bv[8] = {y0.x, y0.y, y0.z, y0.w, y1.x, y1.y, y1.z, y1.w};
#pragma unroll
      for (int i = 0; i < 8; ++i)
#pragma unroll
        for (int j = 0; j < 8; ++j)
          acc[i][j] = fmaf(av[i], bv[j], acc[i][j]);
    }
  }
  float bias[8];
#pragma unroll
  for (int j = 0; j < 8; ++j) bias[j] = bx[n0 + tx * 8 + j] + bh[n0 + tx * 8 + j];
#pragma unroll
  for (int i = 0; i < 8; ++i) {
    float4 o0, o1;
    o0.x = acc[i][0] + bias[0]; o0.y = acc[i][1] + bias[1];
    o0.z = acc[i][2] + bias[2]; o0.w = acc[i][3] + bias[3];
    o1.x = acc[i][4] + bias[4]; o1.y = acc[i][5] + bias[5];
    o1.z = acc[i][6] + bias[6]; o1.w = acc[i][7] + bias[7];
    size_t off = (size_t)(m0 + ty * 8 + i) * Hdim + n0 + tx * 8;
    *(float4*)&C[off] = o0;
    *(float4*)&C[off + 4] = o1;
  }
}

// ---------------- flag clear (sc1 stores so no dirty L2 copies linger) ------
__global__ void clear_flags(unsigned int* flags) {
  __hip_atomic_store(&flags[threadIdx.x], 0u, __ATOMIC_RELAXED,
                     __HIP_MEMORY_SCOPE_AGENT);
}

// ---------------- Phase 2: persistent recurrent scan ------------------------
// 512 threads = 8 waves. wave w, lane l: kgrp=l/8, cq=l%8.
// Thread holds Wh[w*128+kgrp*16 .. +16)[cbase+cq*4 .. +4): 16 float4 = 64 VGPR.
__global__ __launch_bounds__(512, 2) void rnn_scan(
    const float* __restrict__ Wh,   // [H][H]
    float* __restrict__ out,        // [B][T][H]: xproj in, h out
    float* __restrict__ hlast,      // [B][H]
    float* hbuf,                    // ws: [2][64][1024] fp32
    unsigned int* flags) {          // ws: [8][32]
  const int bid = blockIdx.x;
  const int bg = bid & 7;          // batch group (8 batches)
  const int cg = bid >> 3;         // col group (32 cols)
  const int tid = threadIdx.x;
  const int w = tid >> 6;          // wave 0..7
  const int l = tid & 63;
  const int kgrp = l >> 3;
  const int cq = l & 7;
  const int kbase = w * 128 + kgrp * 16;
  const int cbase = cg * 32;
  const int c4 = cq * 4;
  const int batch0 = bg * 8;

  __shared__ float h_lds[8192] __attribute__((aligned(16)));    // 32 KB
  __shared__ float part[8][8][32] __attribute__((aligned(16))); // 8 KB

  // Persistent Wh slice; asm pin => compiler MUST keep it in VGPRs.
  float4 wh4[16];
#pragma unroll
  for (int i = 0; i < 16; ++i)
    wh4[i] = *(const float4*)&Wh[(size_t)(kbase + i) * Hdim + cbase + c4];
#pragma unroll
  for (int i = 0; i < 16; ++i)
    asm volatile("" : "+v"(wh4[i].x), "+v"(wh4[i].y), "+v"(wh4[i].z),
                      "+v"(wh4[i].w));

  const bool fin = tid < 256;       // finisher: owns one (batch,col) output
  const int fb = (tid >> 5) & 7;
  const int fc = tid & 31;
  const size_t orow = (size_t)(batch0 + fb) * ((size_t)Tdim * Hdim) + cbase + fc;
  const size_t hrow = (size_t)(batch0 + fb) * Hdim + cbase + fc;
  unsigned int* myflags = &flags[bg * 32];

  float xp = fin ? out[orow] : 0.f;  // xproj for t=0
  float sum = 0.f;

  for (int t = 0; t < Tdim; ++t) {
    float h = 0.f;
    if (fin) h = tanh_fast(xp + sum);
    if (t == Tdim - 1) {
      if (fin) {
        out[orow + (size_t)t * Hdim] = h;
        hlast[hrow] = h;
      }
      break;
    }
    // publish h_t (write-through; no L2 state, no fence needed)
    if (fin)
      __hip_atomic_store(&hbuf[(size_t)((t + 1) & 1) * 65536 + hrow], h,
                         __ATOMIC_RELAXED, __HIP_MEMORY_SCOPE_AGENT);
    __syncthreads();  // per-wave s_waitcnt vmcnt(0): all publishes acked
    if (tid == 0)
      __hip_atomic_store(&myflags[cg], (unsigned int)(t + 1), __ATOMIC_RELAXED,
                         __HIP_MEMORY_SCOPE_AGENT);
    if (fin) {
      // off-critical-path: output store + next xproj prefetch
      __builtin_nontemporal_store(h, &out[orow + (size_t)t * Hdim]);
      xp = __builtin_nontemporal_load(&out[orow + (size_t)(t + 1) * Hdim]);
    }
    if (w == 0) {
      const unsigned int tgt = (unsigned int)(t + 1);
      unsigned int* f = &myflags[l & 31];
      while (true) {
        unsigned int v =
            __hip_atomic_load(f, __ATOMIC_RELAXED, __HIP_MEMORY_SCOPE_AGENT);
        if (__ballot(v >= tgt) == ~0ull) break;
        __builtin_amdgcn_s_sleep(1);
      }
    }
    __syncthreads();
    // stage h_t (8 batches x 1024 fp32) into LDS, XOR-swizzled
    {
      const float* src = hbuf + (size_t)((t + 1) & 1) * 65536 +
                         (size_t)batch0 * 1024 + (size_t)tid * 16;
      float hv[16];
#pragma unroll
      for (int i = 0; i < 16; ++i)
        hv[i] = __hip_atomic_load(&src[i], __ATOMIC_RELAXED,
                                  __HIP_MEMORY_SCOPE_AGENT);
      const int L0 = tid * 16;
#pragma unroll
      for (int g = 0; g < 4; ++g) {
        int L = L0 + g * 4;
        int sw = L ^ (((L >> 5) & 7) << 2);
        *(float4*)&h_lds[sw] =
            make_float4(hv[g * 4], hv[g * 4 + 1], hv[g * 4 + 2], hv[g * 4 + 3]);
      }
    }
    __syncthreads();
    // compute: 8 batches x 4 cols x 16 k per thread
#pragma unroll
    for (int b = 0; b < 8; ++b) {
      float p0 = 0.f, p1 = 0.f, p2 = 0.f, p3 = 0.f;
      const int Lb = b * 1024 + kbase;
#pragma unroll
      for (int q = 0; q < 4; ++q) {
        int L = Lb + q * 4;
        int sw = L ^ (((L >> 5) & 7) << 2);
        float4 hv = *(const float4*)&h_lds[sw];
        float4 wa = wh4[4 * q + 0], wb = wh4[4 * q + 1];
        float4 wc = wh4[4 * q + 2], wd = wh4[4 * q + 3];
        p0 = fmaf(hv.x, wa.x, p0); p0 = fmaf(hv.y, wb.x, p0);
        p0 = fmaf(hv.z, wc.x, p0); p0 = fmaf(hv.w, wd.x, p0);
        p1 = fmaf(hv.x, wa.y, p1); p1 = fmaf(hv.y, wb.y, p1);
        p1 = fmaf(hv.z, wc.y, p1); p1 = fmaf(hv.w, wd.y, p1);
        p2 = fmaf(hv.x, wa.z, p2); p2 = fmaf(hv.y, wb.z, p2);
        p2 = fmaf(hv.z, wc.z, p2); p2 = fmaf(hv.w, wd.z, p2);
        p3 = fmaf(hv.x, wa.w, p3); p3 = fmaf(hv.y, wb.w, p3);
        p3 = fmaf(hv.z, wc.w, p3); p3 = fmaf(hv.w, wd.w, p3);
      }
      // butterfly over kgrp (lane bits 3..5)
      p0 += __shfl_xor(p0, 8);  p0 += __shfl_xor(p0, 16); p0 += __shfl_xor(p0, 32);
      p1 += __shfl_xor(p1, 8);  p1 += __shfl_xor(p1, 16); p1 += __shfl_xor(p1, 32);
      p2 += __shfl_xor(p2, 8);  p2 += __shfl_xor(p2, 16); p2 += __shfl_xor(p2, 32);
      p3 += __shfl_xor(p3, 8);  p3 += __shfl_xor(p3, 16); p3 += __shfl_xor(p3, 32);
      if (kgrp == b)
        *(float4*)&part[w][b][c4] = make_float4(p0, p1, p2, p3);
    }
    __syncthreads();
    if (fin)
      sum = part[0][fb][fc] + part[1][fb][fc] + part[2][fb][fc] +
            part[3][fb][fc] + part[4][fb][fc] + part[5][fb][fc] +
            part[6][fb][fc] + part[7][fb][fc];
  }
}

extern "C" void kernel_launch(void* const* d_in, const int* in_sizes, int n_in,
                              void* d_out, int out_size, void* d_ws,
                              size_t ws_size, hipStream_t stream) {
  const float* x  = (const float*)d_in[0];
  const float* Wx = (const float*)d_in[1];
  const float* bx = (const float*)d_in[2];
  const float* Wh = (const float*)d_in[3];
  const float* bh = (const float*)d_in[4];
  float* out = (float*)d_out;
  float* hlast = out + (size_t)Bdim * Tdim * Hdim;
  unsigned int* flags = (unsigned int*)d_ws;           // 1 KB
  float* hbuf = (float*)((char*)d_ws + 4096);          // 512 KB

  clear_flags<<<1, dim3(256), 0, stream>>>(flags);
  dim3 g1(Hdim / BN, Mdim / BM);  // (8, 256)
  xproj_gemm<<<g1, dim3(256), 0, stream>>>(x, Wx, bx, bh, out);
  rnn_scan<<<dim3(256), dim3(512), 0, stream>>>(Wh, out, hlast, hbuf, flags);
}

// Round 5
// 2035.826 us; speedup vs baseline: 4.7173x; 2.5965x over previous
//
#include <hip/hip_runtime.h>

// RNN: B=64, T=512, I=1024, H=1024, fp32 in/out.
// Phase 1: xproj = x @ Wx + bx + bh -> d_out (fp32 SIMT GEMM, unchanged).
// Phase 2: persistent MFMA scan, 64 blocks x 512 thr.
//   grid: cl = bid&3 (batch cluster: 16 batches), cg = bid>>2 (64 cols).
//   cluster = 16 blocks {cl+4*m} -> XCDs {cl, cl+4} under bid%8 round-robin.
//   Wh bf16 B-fragments: 16x bf16x8 per lane (64 VGPR), loaded ONCE, used as
//   direct MFMA operands every step (no alloca, no asm-pin -> no scratch).
//   h exchange: packed 2xbf16 dword publishes (agent relaxed, write-through),
//   flag per block after vmcnt drain, wave7 polls, staging via sc0sc1
//   dwordx4 loads into XOR-swizzled LDS.

#define Bdim 64
#define Tdim 512
#define Idim 1024
#define Hdim 1024
#define Mdim (Bdim * Tdim)  // 32768

typedef __attribute__((ext_vector_type(8))) short bf16x8;
typedef __attribute__((ext_vector_type(4))) float f32x4;
typedef __attribute__((ext_vector_type(4))) unsigned int u32x4;

__device__ __forceinline__ float tanh_fast(float x) {
  float e = __expf(2.0f * x);
  return 1.0f - 2.0f / (e + 1.0f);
}
__device__ __forceinline__ unsigned int f2bf(float f) {
  unsigned int u = __float_as_uint(f);
  return (u + 0x7FFFu + ((u >> 16) & 1u)) >> 16;  // RNE
}

// ---------------- Phase 1: xproj GEMM (fp32 SIMT, 128x128 tile, 8x8/thread) --
#define BM 128
#define BN 128
#define BK 16

__global__ __launch_bounds__(256) void xproj_gemm(
    const float* __restrict__ A, const float* __restrict__ W,
    const float* __restrict__ bx, const float* __restrict__ bh,
    float* __restrict__ C) {
  __shared__ float As[BK][BM];
  __shared__ float Bs[BK][BN];
  const int tid = threadIdx.x;
  const int m0 = blockIdx.y * BM;
  const int n0 = blockIdx.x * BN;
  const int ty = tid >> 4;
  const int tx = tid & 15;
  const int ar = tid & 127;
  const int ah = tid >> 7;
  const int bk = tid >> 4;
  const int bs = tid & 15;

  float acc[8][8];
#pragma unroll
  for (int i = 0; i < 8; ++i)
#pragma unroll
    for (int j = 0; j < 8; ++j) acc[i][j] = 0.f;

  for (int k0 = 0; k0 < Idim; k0 += BK) {
    float4 a0 = *(const float4*)&A[(size_t)(m0 + ar) * Idim + k0 + ah * 8];
    float4 a1 = *(const float4*)&A[(size_t)(m0 + ar) * Idim + k0 + ah * 8 + 4];
    float4 b0 = *(const float4*)&W[(size_t)(k0 + bk) * Hdim + n0 + bs * 8];
    float4 b1 = *(const float4*)&W[(size_t)(k0 + bk) * Hdim + n0 + bs * 8 + 4];
    __syncthreads();
    As[ah * 8 + 0][ar] = a0.x; As[ah * 8 + 1][ar] = a0.y;
    As[ah * 8 + 2][ar] = a0.z; As[ah * 8 + 3][ar] = a0.w;
    As[ah * 8 + 4][ar] = a1.x; As[ah * 8 + 5][ar] = a1.y;
    As[ah * 8 + 6][ar] = a1.z; As[ah * 8 + 7][ar] = a1.w;
    *(float4*)&Bs[bk][bs * 8] = b0;
    *(float4*)&Bs[bk][bs * 8 + 4] = b1;
    __syncthreads();
#pragma unroll
    for (int kk = 0; kk < BK; ++kk) {
      float4 x0 = *(const float4*)&As[kk][ty * 8];
      float4 x1 = *(const float4*)&As[kk][ty * 8 + 4];
      float4 y0 = *(const float4*)&Bs[kk][tx * 8];
      float4 y1 = *(const float4*)&Bs[kk][tx * 8 + 4];
      float av[8] = {x0.x, x0.y, x0.z, x0.w, x1.x, x1.y, x1.z, x1.w};
      float bv[8] = {y0.x, y0.y, y0.z, y0.w, y1.x, y1.y, y1.z, y1.w};
#pragma unroll
      for (int i = 0; i < 8; ++i)
#pragma unroll
        for (int jj = 0; jj < 8; ++jj)
          acc[i][jj] = fmaf(av[i], bv[jj], acc[i][jj]);
    }
  }
  float bias[8];
#pragma unroll
  for (int jj = 0; jj < 8; ++jj)
    bias[jj] = bx[n0 + tx * 8 + jj] + bh[n0 + tx * 8 + jj];
#pragma unroll
  for (int i = 0; i < 8; ++i) {
    float4 o0, o1;
    o0.x = acc[i][0] + bias[0]; o0.y = acc[i][1] + bias[1];
    o0.z = acc[i][2] + bias[2]; o0.w = acc[i][3] + bias[3];
    o1.x = acc[i][4] + bias[4]; o1.y = acc[i][5] + bias[5];
    o1.z = acc[i][6] + bias[6]; o1.w = acc[i][7] + bias[7];
    size_t off = (size_t)(m0 + ty * 8 + i) * Hdim + n0 + tx * 8;
    *(float4*)&C[off] = o0;
    *(float4*)&C[off + 4] = o1;
  }
}

// ---------------- flag clear --------------------------------------------------
__global__ void clear_flags(unsigned int* flags) {
  __hip_atomic_store(&flags[threadIdx.x], 0u, __ATOMIC_RELAXED,
                     __HIP_MEMORY_SCOPE_AGENT);
}

// ---------------- Phase 2: persistent MFMA scan -------------------------------
__global__ __launch_bounds__(512, 2) void rnn_scan(
    const float* __restrict__ Wh,   // [1024][1024] fp32 (k-major)
    float* __restrict__ out,        // [B][T][H]: xproj in, h out
    float* __restrict__ hlast,      // [B][H]
    unsigned int* hbuf,             // ws: [2][64][512] dwords (2xbf16 each)
    unsigned int* flags) {          // ws: [4][16]
  const int bid = blockIdx.x;
  const int cl = bid & 3;   // batch cluster: batches cl*16 .. +16
  const int cg = bid >> 2;  // col group:    cols   cg*64 .. +64
  const int tid = threadIdx.x;
  const int w = tid >> 6;   // wave 0..7 (k-slice w*128 .. +128)
  const int l = tid & 63;
  const int n0 = cg * 64;

  __shared__ char smem[32768 + 33280] __attribute__((aligned(16)));
  char* smh = smem;          // h tile: [16 b][2048 B] bf16, XOR-swizzled
  char* smp = smem + 32768;  // part:   [8 w][4 nt][65][16 B] f32x4

  // ---- B fragments: Wh bf16, resident in VGPRs for all 512 steps ----
  // lane l: col = n0 + nt*16 + (l&15); k = w*128 + kt*32 + (l>>4)*8 + j
  bf16x8 bfrag[16];
  {
    const int col = n0 + (l & 15);
    const int kr0 = (w << 7) + ((l >> 4) << 3);
#pragma unroll
    for (int nt = 0; nt < 4; ++nt)
#pragma unroll
      for (int kt = 0; kt < 4; ++kt) {
        bf16x8 v;
#pragma unroll
        for (int j = 0; j < 8; ++j)
          v[j] = (short)f2bf(Wh[(size_t)(kr0 + kt * 32 + j) * Hdim + col + nt * 16]);
        bfrag[nt * 4 + kt] = v;
      }
  }

  // finisher ownership: (batch fb, col pair c0=2j)
  const int fb = tid >> 5;
  const int jj = tid & 31;
  const int c0 = 2 * jj;
  const int b_abs = cl * 16 + fb;
  const int nt0 = c0 >> 4;
  const int lane0 = ((fb >> 2) << 4) | (c0 & 15);
  const int reg4 = (fb & 3) * 4;
  const size_t obase = ((size_t)b_abs * Tdim) * Hdim + n0 + c0;
  unsigned int* pub0 = hbuf + (size_t)b_abs * 512 + (n0 >> 1) + jj;
  unsigned int* myflag = &flags[cl * 16 + cg];
  const unsigned int* pollf = &flags[cl * 16 + (l & 15)];

  float2 xp = *(const float2*)&out[obase];  // xproj t=0

  for (int t = 0; t < Tdim; ++t) {
    float sum0 = 0.f, sum1 = 0.f;
    if (t > 0) {
      // A fragments from swizzled LDS: row = l&15, k-slice of wave w
      const int arow = l & 15;
      const int ab = arow * 2048 + (w << 8) + ((l >> 4) << 4);
      const int sw = (arow & 7) << 4;
      bf16x8 af[4];
#pragma unroll
      for (int kt = 0; kt < 4; ++kt)
        af[kt] = *(const bf16x8*)(smh + ((ab + kt * 64) ^ sw));
#pragma unroll
      for (int nt = 0; nt < 4; ++nt) {
        f32x4 a = {0.f, 0.f, 0.f, 0.f};
#pragma unroll
        for (int kt = 0; kt < 4; ++kt)
          a = __builtin_amdgcn_mfma_f32_16x16x32_bf16(af[kt], bfrag[nt * 4 + kt],
                                                      a, 0, 0, 0);
        *(f32x4*)(smp + (((w * 4 + nt) * 65 + l) << 4)) = a;
      }
      __syncthreads();  // #A
#pragma unroll
      for (int w8 = 0; w8 < 8; ++w8) {
        const char* p0 = smp + (((w8 * 4 + nt0) * 65 + lane0) << 4) + reg4;
        sum0 += *(const float*)p0;
        sum1 += *(const float*)(p0 + 16);  // lane0+1
      }
    }
    float h0 = tanh_fast(xp.x + sum0);
    float h1 = tanh_fast(xp.y + sum1);
    if (t == Tdim - 1) {
      *(float2*)&out[obase + (size_t)t * Hdim] = make_float2(h0, h1);
      *(float2*)&hlast[(size_t)b_abs * Hdim + n0 + c0] = make_float2(h0, h1);
      break;
    }
    // publish packed bf16 pair (write-through to coherence point)
    unsigned int pv = (f2bf(h1) << 16) | f2bf(h0);
    __hip_atomic_store(pub0 + (((t + 1) & 1) ? 32768 : 0), pv, __ATOMIC_RELAXED,
                       __HIP_MEMORY_SCOPE_AGENT);
    __syncthreads();  // #B: per-wave vmcnt(0) -> all publishes acked
    if (tid == 0)
      __hip_atomic_store(myflag, (unsigned int)(t + 1), __ATOMIC_RELAXED,
                         __HIP_MEMORY_SCOPE_AGENT);
    if (w == 7) {  // poller wave: no outstanding VMEM -> clean poll loop
      const unsigned int tgt = (unsigned int)(t + 1);
      while (true) {
        unsigned int v = __hip_atomic_load(pollf, __ATOMIC_RELAXED,
                                           __HIP_MEMORY_SCOPE_AGENT);
        if (__ballot(v >= tgt) == ~0ull) break;
        __builtin_amdgcn_s_sleep(1);
      }
    }
    // off-critical-path: output store + next xproj (wave7 does it post-poll)
    *(float2*)&out[obase + (size_t)t * Hdim] = make_float2(h0, h1);
    xp = *(const float2*)&out[obase + (size_t)(t + 1) * Hdim];
    __syncthreads();  // #C: flags observed by all
    // stage h_{t+1}: 2048 x 16B chunks, sc0sc1 loads -> swizzled LDS
    {
      const char* src = (const char*)hbuf + (((t + 1) & 1) ? 131072 : 0) +
                        cl * 32768;
      u32x4 d0, d1, d2, d3;
      const char* p0 = src + (size_t)tid * 16;
      const char* p1 = src + (size_t)(tid + 512) * 16;
      const char* p2 = src + (size_t)(tid + 1024) * 16;
      const char* p3 = src + (size_t)(tid + 1536) * 16;
      asm volatile("global_load_dwordx4 %0, %1, off sc0 sc1" : "=v"(d0) : "v"(p0) : "memory");
      asm volatile("global_load_dwordx4 %0, %1, off sc0 sc1" : "=v"(d1) : "v"(p1) : "memory");
      asm volatile("global_load_dwordx4 %0, %1, off sc0 sc1" : "=v"(d2) : "v"(p2) : "memory");
      asm volatile("global_load_dwordx4 %0, %1, off sc0 sc1" : "=v"(d3) : "v"(p3) : "memory");
      asm volatile("s_waitcnt vmcnt(0)" ::: "memory");
      __builtin_amdgcn_sched_barrier(0);
      int c, row, bl;
      c = tid;        row = c >> 7; bl = (c << 4) ^ ((row & 7) << 4); *(u32x4*)(smh + bl) = d0;
      c = tid + 512;  row = c >> 7; bl = (c << 4) ^ ((row & 7) << 4); *(u32x4*)(smh + bl) = d1;
      c = tid + 1024; row = c >> 7; bl = (c << 4) ^ ((row & 7) << 4); *(u32x4*)(smh + bl) = d2;
      c = tid + 1536; row = c >> 7; bl = (c << 4) ^ ((row & 7) << 4); *(u32x4*)(smh + bl) = d3;
    }
    __syncthreads();  // #D: h_{t+1} staged
  }
}

extern "C" void kernel_launch(void* const* d_in, const int* in_sizes, int n_in,
                              void* d_out, int out_size, void* d_ws,
                              size_t ws_size, hipStream_t stream) {
  const float* x  = (const float*)d_in[0];
  const float* Wx = (const float*)d_in[1];
  const float* bx = (const float*)d_in[2];
  const float* Wh = (const float*)d_in[3];
  const float* bh = (const float*)d_in[4];
  float* out = (float*)d_out;
  float* hlast = out + (size_t)Bdim * Tdim * Hdim;
  unsigned int* flags = (unsigned int*)d_ws;                 // 64 dwords
  unsigned int* hbuf = (unsigned int*)((char*)d_ws + 4096);  // 256 KB

  clear_flags<<<1, dim3(64), 0, stream>>>(flags);
  dim3 g1(Hdim / BN, Mdim / BM);  // (8, 256)
  xproj_gemm<<<g1, dim3(256), 0, stream>>>(x, Wx, bx, bh, out);
  rnn_scan<<<dim3(64), dim3(512), 0, stream>>>(Wh, out, hlast, hbuf, flags);
}

// Round 6
// 1823.636 us; speedup vs baseline: 5.2662x; 1.1164x over previous
//
#include <hip/hip_runtime.h>

// RNN: B=64, T=512, I=1024, H=1024, fp32 in/out.
// Phase 0: transpose-convert Wx -> WxT bf16, Wh -> WhT bf16 (in ws).
// Phase 1: xproj = x @ Wx + bx + bh -> d_out, bf16 MFMA GEMM (fp32 accum),
//          x converted fp32->bf16 on the fly during LDS staging.
// Phase 2: persistent MFMA scan, 64 blocks x 512 thr (R5-verified geometry).
//   Sync: TAGGED 8B slots {u32 tag, 2xbf16} via relaxed agent-scope atomics.
//   One L3 round-trip instead of three (no vmcnt drain, no flags, no poll
//   wave). 2 barriers/step. Double-parity buffer; causality proves a slot
//   for step t can only be overwritten by t+2 after all consumers of t are
//   done. Tags cleared by 512KB memset each launch.

#define Bdim 64
#define Tdim 512
#define Idim 1024
#define Hdim 1024
#define Mdim (Bdim * Tdim)  // 32768

typedef __attribute__((ext_vector_type(8))) short bf16x8;
typedef __attribute__((ext_vector_type(4))) float f32x4;
typedef __attribute__((ext_vector_type(4))) unsigned int u32x4;

__device__ __forceinline__ float tanh_fast(float x) {
  float e = __expf(2.0f * x);
  return 1.0f - 2.0f / (e + 1.0f);
}
__device__ __forceinline__ unsigned int f2bf(float f) {
  unsigned int u = __float_as_uint(f);
  return (u + 0x7FFFu + ((u >> 16) & 1u)) >> 16;  // RNE
}
__device__ __forceinline__ unsigned int pack2(float lo, float hi) {
  return f2bf(lo) | (f2bf(hi) << 16);
}

// ---------------- Phase 0: fp32 [K][N] -> bf16 transposed [N][K] -------------
__global__ __launch_bounds__(256) void cvt_transpose(
    const float* __restrict__ src, unsigned short* __restrict__ dst) {
  __shared__ float t[32][33];
  const int bx = blockIdx.x * 32;  // src col / dst row
  const int by = blockIdx.y * 32;  // src row / dst col
  const int ty = threadIdx.x >> 3;   // 0..31
  const int tx = threadIdx.x & 7;    // 0..7 (x4 cols)
  float4 v = *(const float4*)&src[(size_t)(by + ty) * 1024 + bx + tx * 4];
  t[ty][tx * 4 + 0] = v.x; t[ty][tx * 4 + 1] = v.y;
  t[ty][tx * 4 + 2] = v.z; t[ty][tx * 4 + 3] = v.w;
  __syncthreads();
  ushort4 o;
  o.x = (unsigned short)f2bf(t[tx * 4 + 0][ty]);
  o.y = (unsigned short)f2bf(t[tx * 4 + 1][ty]);
  o.z = (unsigned short)f2bf(t[tx * 4 + 2][ty]);
  o.w = (unsigned short)f2bf(t[tx * 4 + 3][ty]);
  *(ushort4*)&dst[(size_t)(bx + ty) * 1024 + by + tx * 4] = o;
}

// ---------------- Phase 1: bf16 MFMA GEMM, 128x128 tile, BK=32 ---------------
// 256 thr = 4 waves (2x2 of 64x64). A = x fp32 (cvt in staging), B = WxT bf16.
__global__ __launch_bounds__(256) void xg_mfma(
    const float* __restrict__ X,            // [M][K] fp32
    const unsigned short* __restrict__ WxT, // [N][K] bf16
    const float* __restrict__ bx, const float* __restrict__ bh,
    float* __restrict__ C) {                // [M][N] fp32
  __shared__ char sAB[16384] __attribute__((aligned(16)));
  char* sA = sAB;            // [128 m][64B = 32k bf16], XOR swizzled
  char* sB = sAB + 8192;     // [128 n][64B]
  const int tid = threadIdx.x;
  const int m0 = blockIdx.y * 128;
  const int n0 = blockIdx.x * 128;
  const int w = tid >> 6, l = tid & 63;
  const int wm = (w >> 1) * 64, wn = (w & 1) * 64;
  const int r2 = tid >> 1, kh = tid & 1;  // staging: row, k-half

  f32x4 acc[4][4];
#pragma unroll
  for (int i = 0; i < 4; ++i)
#pragma unroll
    for (int j = 0; j < 4; ++j) acc[i][j] = (f32x4){0.f, 0.f, 0.f, 0.f};

  for (int k0 = 0; k0 < Idim; k0 += 32) {
    const float* xa = &X[(size_t)(m0 + r2) * Idim + k0 + kh * 16];
    float4 a0 = *(const float4*)(xa + 0), a1 = *(const float4*)(xa + 4);
    float4 a2 = *(const float4*)(xa + 8), a3 = *(const float4*)(xa + 12);
    const char* wb = (const char*)&WxT[(size_t)(n0 + r2) * Idim + k0 + kh * 16];
    u32x4 b0 = *(const u32x4*)wb;
    u32x4 b1 = *(const u32x4*)(wb + 16);
    __syncthreads();  // previous compute's LDS reads done
    u32x4 pa0 = {pack2(a0.x, a0.y), pack2(a0.z, a0.w),
                 pack2(a1.x, a1.y), pack2(a1.z, a1.w)};
    u32x4 pa1 = {pack2(a2.x, a2.y), pack2(a2.z, a2.w),
                 pack2(a3.x, a3.y), pack2(a3.z, a3.w)};
    const int sw = (r2 & 7) << 4;
    const int rb = r2 * 64 + kh * 32;
    *(u32x4*)(sA + ((rb + 0) ^ sw)) = pa0;
    *(u32x4*)(sA + ((rb + 16) ^ sw)) = pa1;
    *(u32x4*)(sB + ((rb + 0) ^ sw)) = b0;
    *(u32x4*)(sB + ((rb + 16) ^ sw)) = b1;
    __syncthreads();
    bf16x8 af[4], bf[4];
#pragma unroll
    for (int i = 0; i < 4; ++i) {
      int ra = wm + i * 16 + (l & 15);
      af[i] = *(const bf16x8*)(sA + ((ra * 64 + (l >> 4) * 16) ^ ((ra & 7) << 4)));
      int rn = wn + i * 16 + (l & 15);
      bf[i] = *(const bf16x8*)(sB + ((rn * 64 + (l >> 4) * 16) ^ ((rn & 7) << 4)));
    }
#pragma unroll
    for (int i = 0; i < 4; ++i)
#pragma unroll
      for (int j = 0; j < 4; ++j)
        acc[i][j] = __builtin_amdgcn_mfma_f32_16x16x32_bf16(af[i], bf[j],
                                                            acc[i][j], 0, 0, 0);
  }
  float bias[4];
#pragma unroll
  for (int j = 0; j < 4; ++j) {
    int c = n0 + wn + j * 16 + (l & 15);
    bias[j] = bx[c] + bh[c];
  }
#pragma unroll
  for (int i = 0; i < 4; ++i) {
    int rbase = m0 + wm + i * 16 + (l >> 4) * 4;
#pragma unroll
    for (int j = 0; j < 4; ++j) {
      int c = n0 + wn + j * 16 + (l & 15);
#pragma unroll
      for (int r = 0; r < 4; ++r)
        C[(size_t)(rbase + r) * Hdim + c] = acc[i][j][r] + bias[j];
    }
  }
}

// ---------------- Phase 2: persistent MFMA scan (tagged sync) -----------------
__global__ __launch_bounds__(512, 2) void rnn_scan(
    const unsigned short* __restrict__ WhT,  // [N=1024][K=1024] bf16
    float* __restrict__ out,                 // [B][T][H]: xproj in, h out
    float* __restrict__ hlast,               // [B][H]
    unsigned long long* hbuf) {              // ws: [2][64][512] {tag,2xbf16}
  const int bid = blockIdx.x;
  const int cl = bid & 3;   // batch cluster: batches cl*16 .. +16
  const int cg = bid >> 2;  // col group:    cols   cg*64 .. +64
  const int tid = threadIdx.x;
  const int w = tid >> 6;   // wave 0..7 (k-slice w*128 .. +128)
  const int l = tid & 63;
  const int n0 = cg * 64;

  __shared__ char smem[32768 + 33280] __attribute__((aligned(16)));
  char* smh = smem;          // h tile: [16 b][2048 B] bf16, XOR-swizzled
  char* smp = smem + 32768;  // part:   [8 w][4 nt][65][16 B] f32x4

  // B fragments: WhT bf16, resident in VGPRs for all 512 steps.
  // lane l: col = n0 + nt*16 + (l&15); k = w*128 + kt*32 + (l>>4)*8 + j
  bf16x8 bfrag[16];
  {
    const int col = n0 + (l & 15);
    const int kb = (w << 7) + ((l >> 4) << 3);
#pragma unroll
    for (int nt = 0; nt < 4; ++nt)
#pragma unroll
      for (int kt = 0; kt < 4; ++kt)
        bfrag[nt * 4 + kt] =
            *(const bf16x8*)&WhT[(size_t)(col + nt * 16) * 1024 + kb + kt * 32];
  }

  // every thread finishes one (batch, col-pair): 512 thr = 16 b x 32 pairs
  const int fb = tid >> 5;          // 0..15
  const int jj = tid & 31;
  const int c0 = 2 * jj;
  const int b_abs = cl * 16 + fb;
  const int nt0 = c0 >> 4;
  const int lane0 = ((fb >> 2) << 4) | (c0 & 15);
  const int reg4 = (fb & 3) * 4;
  const size_t obase = ((size_t)b_abs * Tdim) * Hdim + n0 + c0;

  float2 xp = *(const float2*)&out[obase];  // xproj t=0

  for (int t = 0; t < Tdim; ++t) {
    float sum0 = 0.f, sum1 = 0.f;
    if (t > 0) {
      const int arow = l & 15;
      const int ab = arow * 2048 + (w << 8) + ((l >> 4) << 4);
      const int sw = (arow & 7) << 4;
      bf16x8 af[4];
#pragma unroll
      for (int kt = 0; kt < 4; ++kt)
        af[kt] = *(const bf16x8*)(smh + ((ab + kt * 64) ^ sw));
#pragma unroll
      for (int nt = 0; nt < 4; ++nt) {
        f32x4 a = {0.f, 0.f, 0.f, 0.f};
#pragma unroll
        for (int kt = 0; kt < 4; ++kt)
          a = __builtin_amdgcn_mfma_f32_16x16x32_bf16(af[kt], bfrag[nt * 4 + kt],
                                                      a, 0, 0, 0);
        *(f32x4*)(smp + (((w * 4 + nt) * 65 + l) << 4)) = a;
      }
      __syncthreads();  // #A: partials visible
#pragma unroll
      for (int w8 = 0; w8 < 8; ++w8) {
        const char* p0 = smp + (((w8 * 4 + nt0) * 65 + lane0) << 4) + reg4;
        sum0 += *(const float*)p0;
        sum1 += *(const float*)(p0 + 16);
      }
    }
    float h0 = tanh_fast(xp.x + sum0);
    float h1 = tanh_fast(xp.y + sum1);
    if (t == Tdim - 1) {
      *(float2*)&out[obase + (size_t)t * Hdim] = make_float2(h0, h1);
      *(float2*)&hlast[(size_t)b_abs * Hdim + n0 + c0] = make_float2(h0, h1);
      break;
    }
    const int par = (t + 1) & 1;
    // publish {tag, 2xbf16} in ONE 8B store -- the only producer-side action
    unsigned long long pv =
        ((unsigned long long)(unsigned int)(t + 1) << 32) |
        (unsigned long long)pack2(h0, h1);
    __hip_atomic_store(&hbuf[(size_t)par * 32768 + (size_t)b_abs * 512 +
                             (n0 >> 1) + jj],
                       pv, __ATOMIC_RELAXED, __HIP_MEMORY_SCOPE_AGENT);
    // off-critical-path: output store + next xproj prefetch
    *(float2*)&out[obase + (size_t)t * Hdim] = make_float2(h0, h1);
    xp = *(const float2*)&out[obase + (size_t)(t + 1) * Hdim];
    // stage h_t: retry-load this thread's 8x16B chunks until tags fresh
    {
      const char* src =
          (const char*)hbuf + (size_t)par * 262144 + (size_t)cl * 65536;
      u32x4 v[8];
      const unsigned int tgt = (unsigned int)(t + 1);
      for (;;) {
#pragma unroll
        for (int i = 0; i < 8; ++i) {
          const char* p = src + ((size_t)(tid + i * 512) << 4);
          asm volatile("global_load_dwordx4 %0, %1, off sc0 sc1"
                       : "=v"(v[i]) : "v"(p) : "memory");
        }
        asm volatile("s_waitcnt vmcnt(0)" ::: "memory");
        bool ok = true;
#pragma unroll
        for (int i = 0; i < 8; ++i)
          ok = ok && (v[i].y >= tgt) && (v[i].w >= tgt);
        if (ok) break;
        __builtin_amdgcn_s_sleep(1);
      }
      __builtin_amdgcn_sched_barrier(0);
#pragma unroll
      for (int i = 0; i < 8; ++i) {
        int chunk = tid + i * 512;
        int bl = chunk >> 8;           // batch row 0..15
        int cp0 = (chunk << 1) & 511;  // even col-pair index
        int byte = (bl * 2048 + cp0 * 4) ^ ((bl & 7) << 4);
        *(uint2*)(smh + byte) = make_uint2(v[i].x, v[i].z);
      }
    }
    __syncthreads();  // #D: h_t staged for everyone
  }
}

extern "C" void kernel_launch(void* const* d_in, const int* in_sizes, int n_in,
                              void* d_out, int out_size, void* d_ws,
                              size_t ws_size, hipStream_t stream) {
  const float* x  = (const float*)d_in[0];
  const float* Wx = (const float*)d_in[1];
  const float* bx = (const float*)d_in[2];
  const float* Wh = (const float*)d_in[3];
  const float* bh = (const float*)d_in[4];
  float* out = (float*)d_out;
  float* hlast = out + (size_t)Bdim * Tdim * Hdim;
  unsigned long long* hbuf = (unsigned long long*)d_ws;            // 512 KB
  unsigned short* WxT = (unsigned short*)((char*)d_ws + 524288);   // 2 MB
  unsigned short* WhT = (unsigned short*)((char*)d_ws + 524288 + 2097152);

  // clear tags each launch (ws is NOT re-poisoned between graph replays)
  hipMemsetAsync(d_ws, 0, 524288, stream);

  dim3 gt(32, 32);
  cvt_transpose<<<gt, dim3(256), 0, stream>>>(Wx, WxT);
  cvt_transpose<<<gt, dim3(256), 0, stream>>>(Wh, WhT);
  xg_mfma<<<dim3(Hdim / 128, Mdim / 128), dim3(256), 0, stream>>>(x, WxT, bx,
                                                                  bh, out);
  rnn_scan<<<dim3(64), dim3(512), 0, stream>>>(WhT, out, hlast, hbuf);
}

// Round 7
// 1545.853 us; speedup vs baseline: 6.2126x; 1.1797x over previous
//
#include <hip/hip_runtime.h>

// RNN: B=64, T=512, I=1024, H=1024, fp32 in/out.
// Phase 0: transpose-convert Wx/Wh -> bf16 [N][K] in ws.
// Phase 1: xproj = x @ Wx + bx + bh (bf16 MFMA, fp32 accum) -> d_out.
// Phase 2: persistent MFMA scan, 64 blocks x 512 thr = 8 clusters x 8 members.
//   cluster c: batches c*8..+8; member m: cols m*128..+128.
//   Wh slice [1024k x 128c] bf16 = 32 B-frags = 128 VGPR/lane, loaded once.
//   Flag protocol (R5-proven, MALL-based, correct under any XCD placement):
//     publish h (agent relaxed) -> s_waitcnt vmcnt(2) -> raw barrier ->
//     tid0 flag -> wave7 polls 8 flags (one line) -> raw barrier ->
//     single-shot staging (sc0 sc1) -> LDS. Raw barriers + counted vmcnt
//     keep the HBM out-store/xp-prefetch OFF the sync critical path.

#define Bdim 64
#define Tdim 512
#define Idim 1024
#define Hdim 1024
#define Mdim (Bdim * Tdim)  // 32768

typedef __attribute__((ext_vector_type(8))) short bf16x8;
typedef __attribute__((ext_vector_type(4))) float f32x4;
typedef __attribute__((ext_vector_type(4))) unsigned int u32x4;

__device__ __forceinline__ float tanh_fast(float x) {
  float e = __expf(2.0f * x);
  return 1.0f - 2.0f / (e + 1.0f);
}
__device__ __forceinline__ unsigned int f2bf(float f) {
  unsigned int u = __float_as_uint(f);
  return (u + 0x7FFFu + ((u >> 16) & 1u)) >> 16;  // RNE
}
__device__ __forceinline__ unsigned int pack2(float lo, float hi) {
  return f2bf(lo) | (f2bf(hi) << 16);
}

// ---------------- Phase 0: fp32 [K][N] -> bf16 transposed [N][K] -------------
__global__ __launch_bounds__(256) void cvt_transpose(
    const float* __restrict__ src, unsigned short* __restrict__ dst) {
  __shared__ float t[32][33];
  const int bx = blockIdx.x * 32;
  const int by = blockIdx.y * 32;
  const int ty = threadIdx.x >> 3;
  const int tx = threadIdx.x & 7;
  float4 v = *(const float4*)&src[(size_t)(by + ty) * 1024 + bx + tx * 4];
  t[ty][tx * 4 + 0] = v.x; t[ty][tx * 4 + 1] = v.y;
  t[ty][tx * 4 + 2] = v.z; t[ty][tx * 4 + 3] = v.w;
  __syncthreads();
  ushort4 o;
  o.x = (unsigned short)f2bf(t[tx * 4 + 0][ty]);
  o.y = (unsigned short)f2bf(t[tx * 4 + 1][ty]);
  o.z = (unsigned short)f2bf(t[tx * 4 + 2][ty]);
  o.w = (unsigned short)f2bf(t[tx * 4 + 3][ty]);
  *(ushort4*)&dst[(size_t)(bx + ty) * 1024 + by + tx * 4] = o;
}

// ---------------- Phase 1: bf16 MFMA GEMM, 128x128 tile, BK=32 ---------------
__global__ __launch_bounds__(256) void xg_mfma(
    const float* __restrict__ X,            // [M][K] fp32
    const unsigned short* __restrict__ WxT, // [N][K] bf16
    const float* __restrict__ bx, const float* __restrict__ bh,
    float* __restrict__ C) {                // [M][N] fp32
  __shared__ char sAB[16384] __attribute__((aligned(16)));
  char* sA = sAB;
  char* sB = sAB + 8192;
  const int tid = threadIdx.x;
  const int m0 = blockIdx.y * 128;
  const int n0 = blockIdx.x * 128;
  const int w = tid >> 6, l = tid & 63;
  const int wm = (w >> 1) * 64, wn = (w & 1) * 64;
  const int r2 = tid >> 1, kh = tid & 1;

  f32x4 acc[4][4];
#pragma unroll
  for (int i = 0; i < 4; ++i)
#pragma unroll
    for (int j = 0; j < 4; ++j) acc[i][j] = (f32x4){0.f, 0.f, 0.f, 0.f};

  for (int k0 = 0; k0 < Idim; k0 += 32) {
    const float* xa = &X[(size_t)(m0 + r2) * Idim + k0 + kh * 16];
    float4 a0 = *(const float4*)(xa + 0), a1 = *(const float4*)(xa + 4);
    float4 a2 = *(const float4*)(xa + 8), a3 = *(const float4*)(xa + 12);
    const char* wb = (const char*)&WxT[(size_t)(n0 + r2) * Idim + k0 + kh * 16];
    u32x4 b0 = *(const u32x4*)wb;
    u32x4 b1 = *(const u32x4*)(wb + 16);
    __syncthreads();
    u32x4 pa0 = {pack2(a0.x, a0.y), pack2(a0.z, a0.w),
                 pack2(a1.x, a1.y), pack2(a1.z, a1.w)};
    u32x4 pa1 = {pack2(a2.x, a2.y), pack2(a2.z, a2.w),
                 pack2(a3.x, a3.y), pack2(a3.z, a3.w)};
    const int sw = (r2 & 7) << 4;
    const int rb = r2 * 64 + kh * 32;
    *(u32x4*)(sA + ((rb + 0) ^ sw)) = pa0;
    *(u32x4*)(sA + ((rb + 16) ^ sw)) = pa1;
    *(u32x4*)(sB + ((rb + 0) ^ sw)) = b0;
    *(u32x4*)(sB + ((rb + 16) ^ sw)) = b1;
    __syncthreads();
    bf16x8 af[4], bf[4];
#pragma unroll
    for (int i = 0; i < 4; ++i) {
      int ra = wm + i * 16 + (l & 15);
      af[i] = *(const bf16x8*)(sA + ((ra * 64 + (l >> 4) * 16) ^ ((ra & 7) << 4)));
      int rn = wn + i * 16 + (l & 15);
      bf[i] = *(const bf16x8*)(sB + ((rn * 64 + (l >> 4) * 16) ^ ((rn & 7) << 4)));
    }
#pragma unroll
    for (int i = 0; i < 4; ++i)
#pragma unroll
      for (int j = 0; j < 4; ++j)
        acc[i][j] = __builtin_amdgcn_mfma_f32_16x16x32_bf16(af[i], bf[j],
                                                            acc[i][j], 0, 0, 0);
  }
  float bias[4];
#pragma unroll
  for (int j = 0; j < 4; ++j) {
    int cc = n0 + wn + j * 16 + (l & 15);
    bias[j] = bx[cc] + bh[cc];
  }
#pragma unroll
  for (int i = 0; i < 4; ++i) {
    int rbase = m0 + wm + i * 16 + (l >> 4) * 4;
#pragma unroll
    for (int j = 0; j < 4; ++j) {
      int cc = n0 + wn + j * 16 + (l & 15);
#pragma unroll
      for (int r = 0; r < 4; ++r)
        C[(size_t)(rbase + r) * Hdim + cc] = acc[i][j][r] + bias[j];
    }
  }
}

// ---------------- flag clear (agent stores -> MALL; no dirty L2 lines) -------
__global__ void clear_flags(unsigned int* flags) {
  __hip_atomic_store(&flags[threadIdx.x], 0u, __ATOMIC_RELAXED,
                     __HIP_MEMORY_SCOPE_AGENT);
}

// ---------------- Phase 2: persistent MFMA scan ------------------------------
__global__ __launch_bounds__(512, 2) void rnn_scan(
    const unsigned short* __restrict__ WhT,  // [N=1024][K=1024] bf16
    float* __restrict__ out,                 // [B][T][H]: xproj in, h out
    float* __restrict__ hlast,               // [B][H]
    unsigned int* hbuf,                      // ws: [2][64 b][512 cp] dwords
    unsigned int* flags) {                   // ws: [8 cl][32] (128B/cluster)
  const int bid = blockIdx.x;
  const int c = bid & 7;   // cluster: batches c*8..+8 (XCD c under round-robin)
  const int m = bid >> 3;  // member: cols m*128..+128
  const int tid = threadIdx.x;
  const int w = tid >> 6;  // wave 0..7: k-slice w*128..+128
  const int l = tid & 63;
  const int n0 = m * 128;

  __shared__ char smem[16384 + 66560] __attribute__((aligned(16)));
  char* smh = smem;          // h: [8 b][2048 B] bf16, XOR-swizzled
  char* smp = smem + 16384;  // partials: [8 w][8 nt][65][16 B]

  // B-frags: Wh[k=w*128..+128][cols n0..+128] -> 8 nt x 4 kt = 128 VGPR/lane
  bf16x8 bfrag[32];
  {
    const int kb = (w << 7) + ((l >> 4) << 3);
    const int col = n0 + (l & 15);
#pragma unroll
    for (int nt = 0; nt < 8; ++nt)
#pragma unroll
      for (int kt = 0; kt < 4; ++kt)
        bfrag[nt * 4 + kt] =
            *(const bf16x8*)&WhT[(size_t)(col + nt * 16) * 1024 + kb + kt * 32];
  }

  // finisher: thread owns (batch fb = w, col pair c0)
  const int fb = tid >> 6;
  const int cpl = tid & 63;
  const int c0 = cpl * 2;
  const int b_abs = c * 8 + fb;
  const int nt0 = c0 >> 4;
  const int lane0 = ((fb >> 2) << 4) | (c0 & 15);
  const int regb = (fb & 3) * 4;
  const size_t obase = (size_t)b_abs * ((size_t)Tdim * Hdim) + n0 + c0;
  unsigned int* pub = &hbuf[(size_t)b_abs * 512 + m * 64 + cpl];
  unsigned int* myflag = &flags[c * 32 + m];
  const unsigned int* pollf = &flags[c * 32 + (l & 7)];

  float2 xp = *(const float2*)&out[obase];  // xproj t=0

  for (int t = 0; t < Tdim; ++t) {
    float sum0 = 0.f, sum1 = 0.f;
    if (t > 0) {
      // A-frags from swizzled LDS (rows = 8 batches; rows 8..15 unused dup)
      const int arow = l & 7;
      const int abase = arow * 2048 + (w << 8) + ((l >> 4) << 4);
      const int sw = arow << 4;
      bf16x8 af[4];
#pragma unroll
      for (int kt = 0; kt < 4; ++kt)
        af[kt] = *(const bf16x8*)(smh + ((abase + kt * 64) ^ sw));
#pragma unroll
      for (int nt = 0; nt < 8; ++nt) {
        f32x4 a = {0.f, 0.f, 0.f, 0.f};
#pragma unroll
        for (int kt = 0; kt < 4; ++kt)
          a = __builtin_amdgcn_mfma_f32_16x16x32_bf16(af[kt], bfrag[nt * 4 + kt],
                                                      a, 0, 0, 0);
        *(f32x4*)(smp + (((w * 8 + nt) * 65 + l) << 4)) = a;
      }
      asm volatile("s_waitcnt lgkmcnt(0)" ::: "memory");
      __builtin_amdgcn_s_barrier();  // #A: partials visible
      asm volatile("" ::: "memory");
#pragma unroll
      for (int w8 = 0; w8 < 8; ++w8) {
        const char* p = smp + (((w8 * 8 + nt0) * 65 + lane0) << 4) + regb;
        sum0 += *(const float*)p;
        sum1 += *(const float*)(p + 16);
      }
    }
    float h0 = tanh_fast(xp.x + sum0);
    float h1 = tanh_fast(xp.y + sum1);
    if (t == Tdim - 1) {
      *(float2*)&out[obase + (size_t)t * Hdim] = make_float2(h0, h1);
      *(float2*)&hlast[(size_t)b_abs * Hdim + n0 + c0] = make_float2(h0, h1);
      break;
    }
    const int par = (t + 1) & 1;
    // publish FIRST; then let out-store + xp-prefetch float behind it
    __hip_atomic_store(pub + par * 32768, pack2(h0, h1), __ATOMIC_RELAXED,
                       __HIP_MEMORY_SCOPE_AGENT);
    asm volatile("" ::: "memory");
    *(float2*)&out[obase + (size_t)t * Hdim] = make_float2(h0, h1);
    xp = *(const float2*)&out[obase + (size_t)(t + 1) * Hdim];
    // vmcnt queue: [publish, out, xp] -> vmcnt(2) == publish acked at MALL
    asm volatile("s_waitcnt vmcnt(2)" ::: "memory");
    __builtin_amdgcn_s_barrier();  // #B: all waves' publishes acked
    asm volatile("" ::: "memory");
    if (tid == 0)
      __hip_atomic_store(myflag, (unsigned int)(t + 1), __ATOMIC_RELAXED,
                         __HIP_MEMORY_SCOPE_AGENT);
    if (w == 7) {  // poll 8 flags (one 32B line per cluster)
      const unsigned int tgt = (unsigned int)(t + 1);
      for (;;) {
        unsigned int v;
        asm volatile(
            "global_load_dword %0, %1, off sc0 sc1\n\ts_waitcnt vmcnt(0)"
            : "=v"(v) : "v"(pollf) : "memory");
        if (__ballot(v >= tgt) == ~0ull) break;
        __builtin_amdgcn_s_sleep(2);
      }
    }
    asm volatile("" ::: "memory");
    __builtin_amdgcn_s_barrier();  // #C: flags observed
    asm volatile("" ::: "memory");
    // single-shot staging: 8 b x 1024 cols bf16 (16 KB) -> swizzled LDS
    {
      const char* src = (const char*)hbuf + (size_t)par * 131072 +
                        (size_t)(c * 8 + (tid >> 6)) * 2048 + (tid & 63) * 32;
      u32x4 d0, d1;
      asm volatile(
          "global_load_dwordx4 %0, %2, off sc0 sc1\n\t"
          "global_load_dwordx4 %1, %2, off offset:16 sc0 sc1\n\t"
          "s_waitcnt vmcnt(0)"
          : "=&v"(d0), "=&v"(d1) : "v"(src) : "memory");
      __builtin_amdgcn_sched_barrier(0);
      const int r = tid >> 6;
      const int base = r * 2048 + (tid & 63) * 32;
      const int sw = r << 4;
      *(u32x4*)(smh + (base ^ sw)) = d0;
      *(u32x4*)(smh + ((base + 16) ^ sw)) = d1;
    }
    asm volatile("s_waitcnt lgkmcnt(0)" ::: "memory");
    __builtin_amdgcn_s_barrier();  // #D: h_t staged
    asm volatile("" ::: "memory");
  }
}

extern "C" void kernel_launch(void* const* d_in, const int* in_sizes, int n_in,
                              void* d_out, int out_size, void* d_ws,
                              size_t ws_size, hipStream_t stream) {
  const float* x  = (const float*)d_in[0];
  const float* Wx = (const float*)d_in[1];
  const float* bx = (const float*)d_in[2];
  const float* Wh = (const float*)d_in[3];
  const float* bh = (const float*)d_in[4];
  float* out = (float*)d_out;
  float* hlast = out + (size_t)Bdim * Tdim * Hdim;
  unsigned int* flags = (unsigned int*)d_ws;                       // 1 KB
  unsigned int* hbuf = (unsigned int*)((char*)d_ws + 4096);        // 256 KB
  unsigned short* WxT = (unsigned short*)((char*)d_ws + 4096 + 262144);
  unsigned short* WhT = (unsigned short*)((char*)d_ws + 4096 + 262144 + 2097152);

  clear_flags<<<1, dim3(256), 0, stream>>>(flags);
  dim3 gt(32, 32);
  cvt_transpose<<<gt, dim3(256), 0, stream>>>(Wx, WxT);
  cvt_transpose<<<gt, dim3(256), 0, stream>>>(Wh, WhT);
  xg_mfma<<<dim3(Hdim / 128, Mdim / 128), dim3(256), 0, stream>>>(x, WxT, bx,
                                                                  bh, out);
  rnn_scan<<<dim3(64), dim3(512), 0, stream>>>(WhT, out, hlast, hbuf, flags);
}